// Round 1
// baseline (345.904 us; speedup 1.0000x reference)
//
#include <hip/hip_runtime.h>
#include <stdint.h>

#define D_MODEL 1024
#define SEQ 2048
#define NHEADS 16

typedef __attribute__((ext_vector_type(8))) short bf16x8v;   // 8 bf16 in 4 VGPRs
typedef __attribute__((ext_vector_type(4))) float f32x4v;    // MFMA accumulator

__device__ __forceinline__ unsigned short f2bf(float f) {
  unsigned int u = __float_as_uint(f);
  u += 0x7fffu + ((u >> 16) & 1u);   // RNE
  return (unsigned short)(u >> 16);
}

__device__ __forceinline__ void gload_lds16(const void* g, void* l) {
  __builtin_amdgcn_global_load_lds(
      (const __attribute__((address_space(1))) unsigned int*)g,
      (__attribute__((address_space(3))) unsigned int*)l, 16, 0, 0);
}

// ---------------- fp32 -> bf16 conversion (8 elems/thread) ----------------
__global__ void cvt8(const float4* __restrict__ src, uint4* __restrict__ dst, int n8) {
  int i = blockIdx.x * blockDim.x + threadIdx.x;
  if (i >= n8) return;
  float4 a = src[2 * i], b = src[2 * i + 1];
  uint4 o;
  o.x = (unsigned int)f2bf(a.x) | ((unsigned int)f2bf(a.y) << 16);
  o.y = (unsigned int)f2bf(a.z) | ((unsigned int)f2bf(a.w) << 16);
  o.z = (unsigned int)f2bf(b.x) | ((unsigned int)f2bf(b.y) << 16);
  o.w = (unsigned int)f2bf(b.z) | ((unsigned int)f2bf(b.w) << 16);
  dst[i] = o;
}

// ---------------- C = (A @ W^T + bias) * scale ----------------
// A: MxK bf16 row-major. W: NxK bf16 row-major (torch Linear weight layout).
// 128x128 tile, BK=32, 4 waves (2x2 of 64x64), 16x16x32 bf16 MFMA. m97 structure.
template <bool OUT_BF16>
__global__ __launch_bounds__(256) void gemm_bt(
    const short* __restrict__ A, const short* __restrict__ Bw,
    const float* __restrict__ bias, void* __restrict__ Cout,
    int M, int N, int K, float scale) {
  __shared__ short As[128 * 32];
  __shared__ short Bs[128 * 32];
  const int tid = threadIdx.x;
  const int lane = tid & 63, wid = tid >> 6;
  const int wr = wid >> 1, wc = wid & 1;
  const int r = lane & 15, g = lane >> 4;
  const int bm = blockIdx.x * 128, bn = blockIdx.y * 128;

  f32x4v acc[4][4] = {};

  const int row0 = tid >> 2, ch = tid & 3;          // staging: i = tid (+256)
  const short* Ap  = A  + (size_t)(bm + row0) * K + ch * 8;
  const short* Ap2 = Ap + (size_t)64 * K;
  const short* Bp  = Bw + (size_t)(bn + row0) * K + ch * 8;
  const short* Bp2 = Bp + (size_t)64 * K;

  for (int k0 = 0; k0 < K; k0 += 32) {
    gload_lds16(Ap + k0,  As + tid * 8);
    gload_lds16(Ap2 + k0, As + tid * 8 + 2048);
    gload_lds16(Bp + k0,  Bs + tid * 8);
    gload_lds16(Bp2 + k0, Bs + tid * 8 + 2048);
    __syncthreads();

    bf16x8v af[4];
#pragma unroll
    for (int m = 0; m < 4; ++m)
      af[m] = *(const bf16x8v*)&As[(wr * 64 + m * 16 + r) * 32 + g * 8];
#pragma unroll
    for (int n = 0; n < 4; ++n) {
      bf16x8v bfr = *(const bf16x8v*)&Bs[(wc * 64 + n * 16 + r) * 32 + g * 8];
#pragma unroll
      for (int m = 0; m < 4; ++m)
        acc[m][n] = __builtin_amdgcn_mfma_f32_16x16x32_bf16(af[m], bfr, acc[m][n], 0, 0, 0);
    }
    __syncthreads();
  }

  float* Cf = (float*)Cout;
  short* Cb = (short*)Cout;
#pragma unroll
  for (int n = 0; n < 4; ++n) {
    int col = bn + wc * 64 + n * 16 + r;
    float bv = bias[col];
#pragma unroll
    for (int m = 0; m < 4; ++m) {
      int rw0 = bm + wr * 64 + m * 16 + g * 4;
#pragma unroll
      for (int j = 0; j < 4; ++j) {
        float v = (acc[m][n][j] + bv) * scale;
        if (OUT_BF16) Cb[(size_t)(rw0 + j) * N + col] = (short)f2bf(v);
        else          Cf[(size_t)(rw0 + j) * N + col] = v;
      }
    }
  }
}

// ---------------- flash attention ----------------
// Q,K,V,O: (B*S, 1024) bf16, head h = columns h*64..h*64+63.
// Q pre-scaled by 0.125*log2(e): softmax in exp2 domain.
// 4 waves x 32 q-rows (QB=128), KV tile 64. Swapped QK^T: S^T = mfma(K, Q)
// so softmax reduce is 2 shuffles and P stays in-register for PV (O^T = V^T P^T).
__global__ __launch_bounds__(256) void flash_attn(
    const short* __restrict__ Qg, const short* __restrict__ Kg,
    const short* __restrict__ Vg, short* __restrict__ Og) {
  __shared__ short Ks[64 * 64];   // [k_row][d], 16B-chunk XOR swizzled by (row&7)
  __shared__ short Vt[64 * 64];   // [d][k],   16B-chunk XOR swizzled by (d&7)
  const int tid = threadIdx.x;
  const int lane = tid & 63, wid = tid >> 6;
  const int r = lane & 15, g = lane >> 4;
  const int bh = blockIdx.y, b = bh >> 4, h = bh & 15;
  const int q0 = blockIdx.x * 128 + wid * 32;
  const int headoff = h * 64;
  const int base = b * SEQ;

  bf16x8v q_frag[2][2];
#pragma unroll
  for (int qf = 0; qf < 2; ++qf)
#pragma unroll
    for (int dc = 0; dc < 2; ++dc)
      q_frag[qf][dc] = *(const bf16x8v*)&Qg[(size_t)(base + q0 + qf * 16 + r) * D_MODEL +
                                            headoff + dc * 32 + g * 8];

  f32x4v o_acc[2][4] = {};
  float m_run[2] = {-1e30f, -1e30f};
  float l_run[2] = {0.f, 0.f};

  for (int k0 = 0; k0 < SEQ; k0 += 64) {
    // stage K (global_load_lds, source-side XOR swizzle; LDS dest linear)
#pragma unroll
    for (int p = 0; p < 2; ++p) {
      int i = tid + p * 256;
      int row = i >> 3, c = i & 7;
      gload_lds16(Kg + (size_t)(base + k0 + row) * D_MODEL + headoff + ((c ^ (row & 7)) * 8),
                  Ks + i * 8);
    }
    // stage V transposed (reg-mediated, swizzled ds writes)
#pragma unroll
    for (int p = 0; p < 4; ++p) {
      int bi = tid + p * 256;
      int d2 = bi & 31, k2 = bi >> 5;
      int d = d2 * 2, k = k2 * 2;
      unsigned int u0 = *(const unsigned int*)&Vg[(size_t)(base + k0 + k) * D_MODEL + headoff + d];
      unsigned int u1 = *(const unsigned int*)&Vg[(size_t)(base + k0 + k + 1) * D_MODEL + headoff + d];
      unsigned int w0 = (u0 & 0xffffu) | (u1 << 16);
      unsigned int w1 = (u0 >> 16) | (u1 & 0xffff0000u);
      int c0 = (k2 >> 2) ^ (d & 7);
      int c1 = (k2 >> 2) ^ ((d + 1) & 7);
      *(unsigned int*)&Vt[d * 64 + c0 * 8 + (k2 & 3) * 2] = w0;
      *(unsigned int*)&Vt[(d + 1) * 64 + c1 * 8 + (k2 & 3) * 2] = w1;
    }
    __syncthreads();

    // S^T[k][q] = K · Q^T
    f32x4v st[2][4] = {};
#pragma unroll
    for (int kb = 0; kb < 4; ++kb) {
      int kr = kb * 16 + r;
#pragma unroll
      for (int dc = 0; dc < 2; ++dc) {
        int ck = (dc * 4 + g) ^ (kr & 7);
        bf16x8v a = *(const bf16x8v*)&Ks[kr * 64 + ck * 8];
#pragma unroll
        for (int qf = 0; qf < 2; ++qf)
          st[qf][kb] = __builtin_amdgcn_mfma_f32_16x16x32_bf16(a, q_frag[qf][dc], st[qf][kb], 0, 0, 0);
      }
    }

    // online softmax (exp2 domain); P packed to bf16 B-frags in-register
    bf16x8v p_frag[2][2];
#pragma unroll
    for (int qf = 0; qf < 2; ++qf) {
      float mx = -1e30f;
#pragma unroll
      for (int kb = 0; kb < 4; ++kb)
#pragma unroll
        for (int j = 0; j < 4; ++j) mx = fmaxf(mx, st[qf][kb][j]);
      mx = fmaxf(mx, __shfl_xor(mx, 16));
      mx = fmaxf(mx, __shfl_xor(mx, 32));
      float mnew = fmaxf(m_run[qf], mx);
      float corr = exp2f(m_run[qf] - mnew);
      float sum = 0.f;
#pragma unroll
      for (int kb = 0; kb < 4; ++kb)
#pragma unroll
        for (int j = 0; j < 4; ++j) {
          float pv = exp2f(st[qf][kb][j] - mnew);
          st[qf][kb][j] = pv;
          sum += pv;
        }
      sum += __shfl_xor(sum, 16);
      sum += __shfl_xor(sum, 32);
      l_run[qf] = l_run[qf] * corr + sum;
      m_run[qf] = mnew;
#pragma unroll
      for (int df = 0; df < 4; ++df)
#pragma unroll
        for (int j = 0; j < 4; ++j) o_acc[qf][df][j] *= corr;
#pragma unroll
      for (int kk = 0; kk < 2; ++kk) {
        bf16x8v pf;
#pragma unroll
        for (int j = 0; j < 4; ++j) {
          pf[j]     = (short)f2bf(st[qf][2 * kk][j]);
          pf[j + 4] = (short)f2bf(st[qf][2 * kk + 1][j]);
        }
        p_frag[qf][kk] = pf;
      }
    }

    // O^T[d][q] += V^T · P^T
#pragma unroll
    for (int df = 0; df < 4; ++df) {
      int d = df * 16 + r;
#pragma unroll
      for (int kk = 0; kk < 2; ++kk) {
        bf16x8v a;
        int c0 = (kk * 4 + (g >> 1)) ^ (r & 7);
        int c1 = (kk * 4 + 2 + (g >> 1)) ^ (r & 7);
        ((uint2*)&a)[0] = *(const uint2*)&Vt[d * 64 + c0 * 8 + (g & 1) * 4];
        ((uint2*)&a)[1] = *(const uint2*)&Vt[d * 64 + c1 * 8 + (g & 1) * 4];
#pragma unroll
        for (int qf = 0; qf < 2; ++qf)
          o_acc[qf][df] = __builtin_amdgcn_mfma_f32_16x16x32_bf16(a, p_frag[qf][kk], o_acc[qf][df], 0, 0, 0);
      }
    }
    __syncthreads();
  }

  // epilogue: O[q][d] = O^T / l
#pragma unroll
  for (int qf = 0; qf < 2; ++qf) {
    float inv = 1.0f / l_run[qf];
    int row = base + q0 + qf * 16 + r;
#pragma unroll
    for (int df = 0; df < 4; ++df) {
      int col = headoff + df * 16 + g * 4;
      uint2 w;
      w.x = (unsigned int)f2bf(o_acc[qf][df][0] * inv) |
            ((unsigned int)f2bf(o_acc[qf][df][1] * inv) << 16);
      w.y = (unsigned int)f2bf(o_acc[qf][df][2] * inv) |
            ((unsigned int)f2bf(o_acc[qf][df][3] * inv) << 16);
      *(uint2*)&Og[(size_t)row * D_MODEL + col] = w;
    }
  }
}

// ---------------- launch ----------------
extern "C" void kernel_launch(void* const* d_in, const int* in_sizes, int n_in,
                              void* d_out, int out_size, void* d_ws, size_t ws_size,
                              hipStream_t stream) {
  const float* q_in = (const float*)d_in[0];
  const float* k_in = (const float*)d_in[1];
  const float* v_in = (const float*)d_in[2];
  const float* WQ = (const float*)d_in[3];
  const float* bQ = (const float*)d_in[4];
  const float* WK = (const float*)d_in[5];
  const float* bK = (const float*)d_in[6];
  const float* WV = (const float*)d_in[7];
  const float* bV = (const float*)d_in[8];
  const float* WO = (const float*)d_in[9];
  const float* bO = (const float*)d_in[10];
  float* out = (float*)d_out;
  char* ws = (char*)d_ws;

  short* wq = (short*)ws;                      // 4 x 2MB weight buffers
  short* wk = wq + (1u << 20);
  short* wv = wk + (1u << 20);
  short* wo = wv + (1u << 20);
  short* Qp = (short*)(ws + (8ull << 20));     // 16MB each
  short* Kp = (short*)(ws + (24ull << 20));
  short* Vp = (short*)(ws + (40ull << 20));
  short* xb = (short*)(ws + (56ull << 20));    // x conversions, then attn output

  const int W8 = (1024 * 1024) / 8;
  const int X8 = (8192 * 1024) / 8;
  const float QSCALE = 0.125f * 1.4426950408889634f;   // 1/sqrt(d_k) * log2(e)

  cvt8<<<W8 / 256, 256, 0, stream>>>((const float4*)WQ, (uint4*)wq, W8);
  cvt8<<<W8 / 256, 256, 0, stream>>>((const float4*)WK, (uint4*)wk, W8);
  cvt8<<<W8 / 256, 256, 0, stream>>>((const float4*)WV, (uint4*)wv, W8);
  cvt8<<<W8 / 256, 256, 0, stream>>>((const float4*)WO, (uint4*)wo, W8);

  cvt8<<<X8 / 256, 256, 0, stream>>>((const float4*)q_in, (uint4*)xb, X8);
  gemm_bt<true><<<dim3(64, 8), 256, 0, stream>>>(xb, wq, bQ, Qp, 8192, 1024, 1024, QSCALE);
  cvt8<<<X8 / 256, 256, 0, stream>>>((const float4*)k_in, (uint4*)xb, X8);
  gemm_bt<true><<<dim3(64, 8), 256, 0, stream>>>(xb, wk, bK, Kp, 8192, 1024, 1024, 1.0f);
  cvt8<<<X8 / 256, 256, 0, stream>>>((const float4*)v_in, (uint4*)xb, X8);
  gemm_bt<true><<<dim3(64, 8), 256, 0, stream>>>(xb, wv, bV, Vp, 8192, 1024, 1024, 1.0f);

  flash_attn<<<dim3(16, 64), 256, 0, stream>>>(Qp, Kp, Vp, xb);

  gemm_bt<false><<<dim3(64, 8), 256, 0, stream>>>(xb, wo, bO, out, 8192, 1024, 1024, 1.0f);
}